// Round 4
// baseline (620.030 us; speedup 1.0000x reference)
//
#include <hip/hip_runtime.h>

// Problem constants
#define D_    1024
#define HH    16
#define DHEAD 64
#define DFF_  4096
#define NTOK  4096   // B*S = 4*1024
#define SQLEN 1024

typedef unsigned short ushort_t;
typedef __attribute__((ext_vector_type(8))) short short8;
typedef __attribute__((ext_vector_type(4))) float floatx4;

#define LOG2E 1.44269504f

__device__ __forceinline__ unsigned short f2bf(float f) {
  union { float f; unsigned u; } x; x.f = f;
  unsigned r = x.u + 0x7fffu + ((x.u >> 16) & 1u);   // RNE
  return (unsigned short)(r >> 16);
}
__device__ __forceinline__ float bf2f(unsigned short u) {
  union { unsigned u; float f; } x; x.u = ((unsigned)u) << 16;
  return x.f;
}
// pack two fp32 -> bf16 pair in 3 ops (round-half-up + v_perm)
__device__ __forceinline__ unsigned pack2bf_fast(float a, float b) {
  union { float f; unsigned u; } x, y; x.f = a; y.f = b;
  return __builtin_amdgcn_perm(y.u + 0x8000u, x.u + 0x8000u, 0x07060302u);
}
__device__ __forceinline__ float fast_exp2(float x) {
  return __builtin_amdgcn_exp2f(x);
}
// gelu(u) = u - u * rcp(exp2(u*(c1 + c2*u^2)) + 1)
__device__ __forceinline__ float fast_gelu(float u) {
  float u2 = u * u;
  float arg = u * (2.30220414f + 0.10294307f * u2);
  float e = __builtin_amdgcn_exp2f(arg);
  float r = __builtin_amdgcn_rcpf(e + 1.0f);
  return u - u * r;
}

__device__ __forceinline__ void async_ld16(const void* g, void* l) {
  __builtin_amdgcn_global_load_lds(
      (const __attribute__((address_space(1))) unsigned int*)g,
      (__attribute__((address_space(3))) unsigned int*)l, 16, 0, 0);
}

// 32-bit LDS byte offset from a generic pointer to __shared__
__device__ __forceinline__ unsigned lds_off(const void* p) {
  return (unsigned)(unsigned long long)
      (const __attribute__((address_space(3))) char*)p;
}
// raw ds_read_b128: invisible to the compiler's vmcnt bookkeeping, so no
// implicit s_waitcnt vmcnt(0) drain is inserted before it (the counted
// VMW waits below are the only VMEM ordering).
__device__ __forceinline__ short8 ds_read128(unsigned addr) {
  short8 r;
  asm volatile("ds_read_b128 %0, %1" : "=v"(r) : "v"(addr));
  return r;
}

// ---------------- prep: cast x + all 6 weight transposes, one launch ----------------
__global__ __launch_bounds__(256) void prep_kernel(
    const float* __restrict__ x, const float* __restrict__ Wq,
    const float* __restrict__ Wk, const float* __restrict__ Wv,
    const float* __restrict__ Wo, const float* __restrict__ W1,
    const float* __restrict__ W2,
    ushort_t* __restrict__ xb, ushort_t* __restrict__ wqkvt,
    ushort_t* __restrict__ wot, ushort_t* __restrict__ w1t,
    ushort_t* __restrict__ w2t) {
  int bid = blockIdx.x, tid = threadIdx.x;
  if (bid < 4096) {
    int i = bid * 256 + tid;
    float4 v = ((const float4*)x)[i];
    ushort4 o;
    o.x = f2bf(v.x); o.y = f2bf(v.y); o.z = f2bf(v.z); o.w = f2bf(v.w);
    ((ushort4*)xb)[i] = o;
    return;
  }
  __shared__ float tile[32][33];
  const float* W; ushort_t* T; int K, N, n0, k0;
  if (bid < 8192) {
    int id = bid - 4096, z = id >> 10, xy = id & 1023;
    W = (z == 0) ? Wq : (z == 1) ? Wk : (z == 2) ? Wv : Wo;
    T = (z < 3) ? wqkvt + (size_t)z * D_ * D_ : wot;
    K = D_; N = D_;
    n0 = (xy & 31) * 32; k0 = (xy >> 5) * 32;
  } else if (bid < 12288) {
    int id = bid - 8192;
    W = W1; T = w1t; K = D_; N = DFF_;
    n0 = (id & 127) * 32; k0 = (id >> 7) * 32;
  } else {
    int id = bid - 12288;
    W = W2; T = w2t; K = DFF_; N = D_;
    n0 = (id & 31) * 32; k0 = (id >> 5) * 32;
  }
  int tx = tid & 31, ty = tid >> 5;
#pragma unroll
  for (int i = 0; i < 4; i++)
    tile[ty + i * 8][tx] = W[(size_t)(k0 + ty + i * 8) * N + n0 + tx];
  __syncthreads();
#pragma unroll
  for (int i = 0; i < 4; i++)
    T[(size_t)(n0 + ty + i * 8) * K + k0 + tx] = f2bf(tile[tx][ty + i * 8]);
}

// ---------------- 256x256 lgkm-pipelined bf16 MFMA GEMM ----------------
// 512 threads = 8 waves (2M x 4N), per-wave output 128x64, BK=64.
// LDS 128 KiB: 2 dbuf x 2 halves x [128][64] bf16 per operand.
// Chunk-XOR swizzle (chunk ^= row&7) applied BOTH sides.
// Register-subtile SOFTWARE PIPELINE: each phase's front issues the ds_reads
// for the NEXT MFMA cluster; s_waitcnt lgkmcnt(N) (N = just-issued count)
// drains only the PREVIOUS cluster's reads -> LDS service overlaps MFMA.
// Dual A reg sets (aP/aQ), tile-parity B0 sets (b0A/b0B), single b1 set;
// 2-tile unrolled body so all reg-set indices are static (rule #20).
// One barrier per phase; every staged half is drained by a per-wave
// counted VMW before the barrier that precedes its ds_read consumption.
// Clusters per tile: C0=(0,0) aP,b0x  C1=(0,1) aP,b1  C2=(1,1) aQ,b1
// C3=(1,0) aQ,b0x.  Stages per tile t (for t+1): A0@ph0 B0@ph1 B1@ph2 A1@ph3.
// vmcnt ledger (2 loads/stage): entry {A1}=2; ph0 +A0' VMW2(drain A1);
// ph1 +B0'; ph2 +B1' VMW2(drain A0',B0'); ph3 +A1' VMW2(drain B1') -> {A1'}=2.
// MODE 0: QKV. q,k -> [B][H][S][DH] bf16 (q scaled 0.125*log2e); v -> [B][H][DH][S]
// MODE 2: gelu(c + bias0[n]) -> bf16 o0[m][n]
// MODE 3: bf16 partial: o0[sp*M*N + m*N + n] = bf16(c)   (reduced in ln_red)
template <int MODE>
__global__ __launch_bounds__(512, 1) void gemm256(
    const ushort_t* __restrict__ A, const ushort_t* __restrict__ Bt,
    int M, int N, int K, int Ks, int nb,
    const float* __restrict__ bias0, const float* __restrict__ bias1,
    const float* __restrict__ bias2,
    ushort_t* __restrict__ o0, ushort_t* __restrict__ o1, ushort_t* __restrict__ o2) {
  __shared__ alignas(16) ushort_t sA[2][2][128 * 64];   // 64 KB
  __shared__ alignas(16) ushort_t sB[2][2][128 * 64];   // 64 KB
  int tid = threadIdx.x;
  int w = tid >> 6, lane = tid & 63, quad = lane >> 4, l16 = lane & 15;
  int wm = w >> 2, wn = w & 3;

  int sp = blockIdx.x / nb;
  int bid = blockIdx.x - sp * nb;
  int gridN = N >> 8;
  int Tn = nb >> 3;                     // tiles per XCD
  int lin = (bid & 7) * Tn + (bid >> 3);
  int ng = gridN << 3;                  // tiles per 8-row m-group
  int gidx = lin / ng;
  int rem = lin - gidx * ng;
  int m0 = ((gidx << 3) + (rem & 7)) << 8;
  int n0 = (rem >> 3) << 8;
  int kbeg = sp * Ks;
  int nkt = Ks >> 6;                    // even, >= 4

  floatx4 acc[8][4];
#pragma unroll
  for (int i = 0; i < 8; i++)
#pragma unroll
    for (int j = 0; j < 4; j++) acc[i][j] = (floatx4){0.f, 0.f, 0.f, 0.f};

  // ---- staging addresses (pre-swizzled global source, linear LDS dest) ----
  int s8  = tid >> 3;                       // 0..63
  int lcx = (tid & 7) ^ (s8 & 7);           // logical chunk for this thread
  const ushort_t* gA = A + (size_t)(m0 + s8) * K + kbeg + lcx * 8;
  const ushort_t* gB = Bt + (size_t)(n0 + (s8 & 31) + (s8 >> 5) * 64) * K + kbeg + lcx * 8;
  char* sta = (char*)&sA[0][0][0] + w * 1024;
  char* stb = (char*)&sB[0][0][0] + w * 1024;

  // ---- read addresses (swizzled chunk) as raw LDS byte offsets ----
  unsigned kof0 = (unsigned)((quad ^ (l16 & 7)) << 4);   // kc=0 chunk byte offset
  unsigned baseA = lds_off(&sA[0][0][0]) + (unsigned)((wm * 64 + l16) * 128);
  unsigned baseB = lds_off(&sB[0][0][0]) + (unsigned)((wn * 32 + l16) * 128);

#define STG_A(db, h, ko) { const ushort_t* _g = gA + (size_t)(h) * 64 * K + (ko); \
    char* _l = sta + (db) * 32768 + (h) * 16384; \
    async_ld16(_g, _l); async_ld16(_g + (size_t)128 * K, _l + 8192); }
#define STG_B(db, h, ko) { const ushort_t* _g = gB + (size_t)(h) * 32 * K + (ko); \
    char* _l = stb + (db) * 32768 + (h) * 16384; \
    async_ld16(_g, _l); async_ld16(_g + (size_t)128 * K, _l + 8192); }
#define LDSA(db, mq, DST) { unsigned _p = baseA + (db) * 32768u + (mq) * 16384u + kof0; \
    _Pragma("unroll") for (int mt = 0; mt < 4; mt++) { \
      DST[mt][0] = ds_read128(_p + (unsigned)(mt * 2048)); \
      DST[mt][1] = ds_read128((_p + (unsigned)(mt * 2048)) ^ 64u); } }
#define LDSB(db, nq, DST) { unsigned _p = baseB + (db) * 32768u + (nq) * 16384u + kof0; \
    _Pragma("unroll") for (int nt = 0; nt < 2; nt++) { \
      DST[nt][0] = ds_read128(_p + (unsigned)(nt * 2048)); \
      DST[nt][1] = ds_read128((_p + (unsigned)(nt * 2048)) ^ 64u); } }
#define MFMAC(mq, nq, A_, B_) { \
    _Pragma("unroll") for (int mt = 0; mt < 4; mt++) \
    _Pragma("unroll") for (int nt = 0; nt < 2; nt++) { \
      floatx4 c = acc[(mq) * 4 + mt][(nq) * 2 + nt]; \
      c = __builtin_amdgcn_mfma_f32_16x16x32_bf16(A_[mt][0], B_[nt][0], c, 0, 0, 0); \
      c = __builtin_amdgcn_mfma_f32_16x16x32_bf16(A_[mt][1], B_[nt][1], c, 0, 0, 0); \
      acc[(mq) * 4 + mt][(nq) * 2 + nt] = c; } }
#define BAR __builtin_amdgcn_s_barrier()
#define LGKC(n) { asm volatile("s_waitcnt lgkmcnt(" #n ")" ::: "memory"); \
                  __builtin_amdgcn_sched_barrier(0); }
#define VMW4 asm volatile("s_waitcnt vmcnt(4)" ::: "memory")
#define VMW2 asm volatile("s_waitcnt vmcnt(2)" ::: "memory")
#define VMW0 asm volatile("s_waitcnt vmcnt(0)" ::: "memory")
#define PRIO1 __builtin_amdgcn_s_setprio(1)
#define PRIO0 __builtin_amdgcn_s_setprio(0)

  short8 aP[4][2], aQ[4][2], b0A[2][2], b0B[2][2], b1[2][2];

  // prologue: stage tile0 (A0,B0,B1,A1); wait A0,B0; pre-read C0 operands;
  // wait B1 (leaves {A1}=2 in flight = steady-state entry)
  STG_A(0, 0, 0); STG_B(0, 0, 0); STG_B(0, 1, 0); STG_A(0, 1, 0);
  VMW4; BAR;
  LDSA(0, 0, aP); LDSB(0, 0, b0A);
  VMW2; BAR;

  for (int kt = 0; kt + 2 < nkt; kt += 2) {
    int ko1 = (kt + 1) << 6, ko2 = (kt + 2) << 6;
    // ---- tile kt (even, buf0, b0A); stages kt+1 -> buf1 ----
    LDSB(0, 1, b1);                 STG_A(1, 0, ko1);
    LGKC(4);  PRIO1; MFMAC(0, 0, aP, b0A); PRIO0; VMW2; BAR;
    LDSA(0, 1, aQ);                 STG_B(1, 0, ko1);
    LGKC(8);  PRIO1; MFMAC(0, 1, aP, b1);  PRIO0;       BAR;
                                    STG_B(1, 1, ko1);
    LGKC(0);  PRIO1; MFMAC(1, 1, aQ, b1);  PRIO0; VMW2; BAR;
    LDSA(1, 0, aP); LDSB(1, 0, b0B); STG_A(1, 1, ko1);
              PRIO1; MFMAC(1, 0, aQ, b0A); PRIO0; VMW2; BAR;
    // ---- tile kt+1 (odd, buf1, b0B); stages kt+2 -> buf0 ----
    LDSB(1, 1, b1);                 STG_A(0, 0, ko2);
    LGKC(4);  PRIO1; MFMAC(0, 0, aP, b0B); PRIO0; VMW2; BAR;
    LDSA(1, 1, aQ);                 STG_B(0, 0, ko2);
    LGKC(8);  PRIO1; MFMAC(0, 1, aP, b1);  PRIO0;       BAR;
                                    STG_B(0, 1, ko2);
    LGKC(0);  PRIO1; MFMAC(1, 1, aQ, b1);  PRIO0; VMW2; BAR;
    LDSA(0, 0, aP); LDSB(0, 0, b0A); STG_A(0, 1, ko2);
              PRIO1; MFMAC(1, 0, aQ, b0B); PRIO0; VMW2; BAR;
  }
  {
    int ko1 = (nkt - 1) << 6;
    // ---- tile nkt-2 (even): normal, stages nkt-1 -> buf1 ----
    LDSB(0, 1, b1);                 STG_A(1, 0, ko1);
    LGKC(4);  PRIO1; MFMAC(0, 0, aP, b0A); PRIO0; VMW2; BAR;
    LDSA(0, 1, aQ);                 STG_B(1, 0, ko1);
    LGKC(8);  PRIO1; MFMAC(0, 1, aP, b1);  PRIO0;       BAR;
                                    STG_B(1, 1, ko1);
    LGKC(0);  PRIO1; MFMAC(1, 1, aQ, b1);  PRIO0; VMW2; BAR;
    LDSA(1, 0, aP); LDSB(1, 0, b0B); STG_A(1, 1, ko1);
              PRIO1; MFMAC(1, 0, aQ, b0A); PRIO0; VMW2; BAR;
    // ---- tile nkt-1 (odd, buf1, b0B): final, no staging ----
    LDSB(1, 1, b1);
    LGKC(4);  PRIO1; MFMAC(0, 0, aP, b0B); PRIO0; VMW0; BAR;
    LDSA(1, 1, aQ);
    LGKC(8);  PRIO1; MFMAC(0, 1, aP, b1);  PRIO0;
    LGKC(0);  PRIO1; MFMAC(1, 1, aQ, b1);  PRIO0;
              PRIO1; MFMAC(1, 0, aQ, b0B); PRIO0;
  }

  // ---------------- epilogue ----------------
  if (MODE == 0) {
#pragma unroll
    for (int bj = 0; bj < 4; bj++) {
      int cg = n0 + wn * 64 + (bj >> 1) * 32 + (bj & 1) * 16 + l16;
      int sel = cg >> 10, nn = cg & 1023;
      const float* bpp = (sel == 0) ? bias0 : ((sel == 1) ? bias1 : bias2);
      float bb = bpp[nn];
      int hh = nn >> 6, dd = nn & 63;
#pragma unroll
      for (int ai = 0; ai < 8; ai++) {
        int rg0 = m0 + wm * 128 + (ai >> 2) * 64 + (ai & 3) * 16 + quad * 4;
        int b0 = rg0 >> 10, s0 = rg0 & 1023;
        if (sel == 2) {
          ushort4 ov;
          ov.x = f2bf(acc[ai][bj][0] + bb);
          ov.y = f2bf(acc[ai][bj][1] + bb);
          ov.z = f2bf(acc[ai][bj][2] + bb);
          ov.w = f2bf(acc[ai][bj][3] + bb);
          *(ushort4*)(o2 + ((size_t)(b0 * HH + hh) * DHEAD + dd) * SQLEN + s0) = ov;
        } else {
          ushort_t* dst = sel ? o1 : o0;
          float sc = (sel == 0) ? (0.125f * LOG2E) : 1.0f;
#pragma unroll
          for (int r = 0; r < 4; r++)
            dst[((size_t)(b0 * HH + hh) * SQLEN + s0 + r) * DHEAD + dd] =
                f2bf((acc[ai][bj][r] + bb) * sc);
        }
      }
    }
  } else {
    size_t rowbase = (size_t)(m0 + wm * 128 + quad * 4) * N + (n0 + wn * 64 + l16);
    if (MODE == 3) rowbase += (size_t)sp * M * N;
    float bb[4];
    if (MODE == 2) {
#pragma unroll
      for (int c = 0; c < 4; c++)
        bb[c] = bias0[(n0 + wn * 64 + c * 16 + l16) & (N - 1)];
    }
#pragma unroll
    for (int ai = 0; ai < 8; ai++) {
#pragma unroll
      for (int r = 0; r < 4; r++) {
        ushort_t* pr = o0 + rowbase + (size_t)((ai >> 2) * 64 + (ai & 3) * 16 + r) * N;
        if (MODE == 2) {
          pr[0]  = f2bf(fast_gelu(acc[ai][0][r] + bb[0]));
          pr[16] = f2bf(fast_gelu(acc[ai][1][r] + bb[1]));
          pr[32] = f2bf(fast_gelu(acc[ai][2][r] + bb[2]));
          pr[48] = f2bf(fast_gelu(acc[ai][3][r] + bb[3]));
        } else {
          pr[0]  = f2bf(acc[ai][0][r]);
          pr[16] = f2bf(acc[ai][1][r]);
          pr[32] = f2bf(acc[ai][2][r]);
          pr[48] = f2bf(acc[ai][3][r]);
        }
      }
    }
  }
#undef STG_A
#undef STG_B
#undef LDSA
#undef LDSB
#undef MFMAC
#undef BAR
#undef LGKC
#undef VMW4
#undef VMW2
#undef VMW0
#undef PRIO1
#undef PRIO0
}

// ---------------- flash attention (S^T form, 128-row q tiles) ----------------
// q,k: [B][H][S][DH] bf16 (q pre-scaled 0.125*log2e). vt: [B][H][DH][S] bf16.
// Block = (bh, 128-row q tile); wave owns 32 q rows (2 groups of 16).
// Fixed-reference exp2 softmax (no running max; scores tiny vs fp32 range).
__global__ __launch_bounds__(256) void flash_attn_kernel(const ushort_t* __restrict__ q,
                                                         const ushort_t* __restrict__ k,
                                                         const ushort_t* __restrict__ vt,
                                                         ushort_t* __restrict__ ctx) {
  __shared__ alignas(16) ushort_t sQ[2][128 * 32];    // 16 KB
  __shared__ alignas(16) ushort_t sK[2][64 * 32];     // 8 KB
  __shared__ alignas(16) ushort_t sVt[2][64 * 32];    // 8 KB
  __shared__ alignas(16) char sP[4][2][2][16 * 80];   // [wave][g][kc], 80B row stride
  int tid = threadIdx.x;
  int w = tid >> 6, lane = tid & 63, quad = lane >> 4, l16 = lane & 15;
  int bh = blockIdx.x, qt = blockIdx.y;
  int b_ = bh >> 4, h_ = bh & 15;

  const ushort_t* Qp = q + ((size_t)bh * SQLEN + qt * 128) * DHEAD;
  const ushort_t* Kp = k + (size_t)bh * SQLEN * DHEAD;
  const ushort_t* Vtp = vt + (size_t)bh * DHEAD * SQLEN;

  int srow = lane >> 2, scol8 = (lane & 3) * 8;

  // stage Q once: 128 rows x 64 cols -> 2 panels of [128][32]
#pragma unroll
  for (int h = 0; h < 2; h++)
#pragma unroll
    for (int p = 0; p < 2; p++)
      async_ld16(Qp + (h * 64 + w * 16 + srow) * 64 + p * 32 + scol8,
                 (char*)sQ + p * 8192 + (h * 64 + w * 16) * 64);

  float l_run[2] = {0.f, 0.f};
  floatx4 o_acc[2][4];
#pragma unroll
  for (int g = 0; g < 2; g++)
#pragma unroll
    for (int dt = 0; dt < 4; dt++) o_acc[g][dt] = (floatx4){0.f, 0.f, 0.f, 0.f};

  for (int kt = 0; kt < 16; kt++) {
    __syncthreads();
#pragma unroll
    for (int t = 0; t < 2; t++) {
      int id = w * 2 + t, panel = id & 1, rg = id >> 1;
      int row = rg * 16 + srow, col = panel * 32 + scol8;
      async_ld16(Kp + kt * 64 * 64 + row * 64 + col,
                 (char*)sK + panel * 4096 + rg * 1024);
      async_ld16(Vtp + (size_t)row * SQLEN + kt * 64 + col,
                 (char*)sVt + panel * 4096 + rg * 1024);
    }
    __syncthreads();

    // S^T = K Q^T for both q-groups (share kf loads)
    floatx4 st[2][4];
#pragma unroll
    for (int g = 0; g < 2; g++)
#pragma unroll
      for (int nt = 0; nt < 4; nt++) st[g][nt] = (floatx4){0.f, 0.f, 0.f, 0.f};
#pragma unroll
    for (int kc = 0; kc < 2; kc++) {
      short8 aq0 = *(const short8*)(sQ[kc] + (w * 32 + l16) * 32 + quad * 8);
      short8 aq1 = *(const short8*)(sQ[kc] + (w * 32 + 16 + l16) * 32 + quad * 8);
#pragma unroll
      for (int nt = 0; nt < 4; nt++) {
        short8 kf = *(const short8*)(sK[kc] + (nt * 16 + l16) * 32 + quad * 8);
        st[0][nt] = __builtin_amdgcn_mfma_f32_16x16x32_bf16(kf, aq0, st[0][nt], 0, 0, 0);
        st[1][nt] = __builtin_amdgcn_mfma_f32_16x16x32_bf16(kf, aq1, st[1][nt], 0, 0, 0);
      }
    }

    // p = exp2(score); per-lane l accumulate; pack + write P (B-operand layout)
#pragma unroll
    for (int g = 0; g < 2; g++) {
#pragma unroll
      for (int nt = 0; nt < 4; nt++) {
        float p0 = fast_exp2(st[g][nt][0]);
        float p1 = fast_exp2(st[g][nt][1]);
        float p2 = fast_exp2(st[g][nt][2]);
        float p3 = fast_exp2(st[g][nt][3]);
        l_run[g] += (p0 + p1) + (p2 + p3);
        uint2 d2;
        d2.x = pack2bf_fast(p0, p1);
        d2.y = pack2bf_fast(p2, p3);
        *(uint2*)(&sP[w][g][nt >> 1][0] + l16 * 80 + (nt & 1) * 32 + quad * 8) = d2;
      }
    }

    // O^T += V^T P^T (share vf loads across groups)
#pragma unroll
    for (int kc = 0; kc < 2; kc++) {
      short8 pf0 = *(const short8*)(&sP[w][0][kc][0] + l16 * 80 + quad * 16);
      short8 pf1 = *(const short8*)(&sP[w][1][kc][0] + l16 * 80 + quad * 16);
#pragma unroll
      for (int dt = 0; dt < 4; dt++) {
        short8 vf = *(const short8*)(sVt[kc] + (dt * 16 + l16) * 32 + quad * 8);
        o_acc[0][dt] = __builtin_amdgcn_mfma_f32_16x16x32_bf16(vf, pf0, o_acc[0][dt], 0, 0, 0);
        o_acc[1][dt] = __builtin_amdgcn_mfma_f32_16x16x32_bf16(vf, pf1, o_acc[1][dt], 0, 0, 0);
      }
    }
  }

#pragma unroll
  for (int g = 0; g < 2; g++) {
    float l = l_run[g];
    l += __shfl_xor(l, 16);
    l += __shfl_xor(l, 32);
    float inv = 1.f / fmaxf(l, 1e-30f);
    int s_ = qt * 128 + w * 32 + g * 16 + l16;
    ushort_t* cp = ctx + (size_t)(b_ * SQLEN + s_) * D_ + h_ * DHEAD + quad * 4;
#pragma unroll
    for (int dt = 0; dt < 4; dt++) {
      ushort4 ov;
      ov.x = f2bf(o_acc[g][dt][0] * inv);
      ov.y = f2bf(o_acc[g][dt][1] * inv);
      ov.z = f2bf(o_acc[g][dt][2] * inv);
      ov.w = f2bf(o_acc[g][dt][3] * inv);
      *(ushort4*)(cp + dt * 16) = ov;
    }
  }
}

// ---------------- LayerNorm with split-K partial reduction ----------------
template <int S, int WB>
__global__ __launch_bounds__(256) void ln_red_kernel(
    const ushort_t* __restrict__ parts, const float* __restrict__ bias,
    const float* __restrict__ res, const float* __restrict__ g,
    const float* __restrict__ b, float* __restrict__ outf,
    ushort_t* __restrict__ outb) {
  int row = blockIdx.x, tid = threadIdx.x;
  float4 v = ((const float4*)(res + (size_t)row * D_))[tid];
  float4 bb = ((const float4*)bias)[tid];
  v.x += bb.x; v.y += bb.y; v.z += bb.z; v.w += bb.w;
#pragma unroll
  for (int s = 0; s < S; s++) {
    ushort4 p = ((const ushort4*)(parts + (size_t)s * NTOK * D_ + (size_t)row * D_))[tid];
    v.x += bf2f(p.x); v.y += bf2f(p.y); v.z += bf2f(p.z); v.w += bf2f(p.w);
  }
  float s1 = v.x + v.y + v.z + v.w;
  float s2 = v.x * v.x + v.y * v.y + v.z * v.z + v.w * v.w;
#pragma unroll
  for (int off = 32; off > 0; off >>= 1) {
    s1 += __shfl_down(s1, off);
    s2 += __shfl_down(s2, off);
  }
  __shared__ float red[10];
  int wid = tid >> 6, lane = tid & 63;
  if (lane == 0) { red[wid] = s1; red[4 + wid] = s2; }
  __syncthreads();
  if (tid == 0) {
    float ts = red[0] + red[1] + red[2] + red[3];
    float ts2 = red[4] + red[5] + red[6] + red[7];
    float mu = ts * (1.f / 1024.f);
    float var = ts2 * (1.f / 1024.f) - mu * mu;
    red[8] = mu;
    red[9] = rsqrtf(var + 1e-5f);
  }
  __syncthreads();
  float mu = red[8], rsg = red[9];
  float4 gv = ((const float4*)g)[tid];
  float4 bv = ((const float4*)b)[tid];
  float4 o;
  o.x = (v.x - mu) * rsg * gv.x + bv.x;
  o.y = (v.y - mu) * rsg * gv.y + bv.y;
  o.z = (v.z - mu) * rsg * gv.z + bv.z;
  o.w = (v.w - mu) * rsg * gv.w + bv.w;
  if (outf) ((float4*)(outf + (size_t)row * D_))[tid] = o;
  if (WB) {
    ushort4 ob;
    ob.x = f2bf(o.x); ob.y = f2bf(o.y); ob.z = f2bf(o.z); ob.w = f2bf(o.w);
    ((ushort4*)(outb + (size_t)row * D_))[tid] = ob;
  }
}

extern "C" void kernel_launch(void* const* d_in, const int* in_sizes, int n_in,
                              void* d_out, int out_size, void* d_ws, size_t ws_size,
                              hipStream_t stream) {
  const float* x   = (const float*)d_in[0];
  const float* Wq  = (const float*)d_in[1];
  const float* bq  = (const float*)d_in[2];
  const float* Wk  = (const float*)d_in[3];
  const float* bk  = (const float*)d_in[4];
  const float* Wv  = (const float*)d_in[5];
  const float* bv  = (const float*)d_in[6];
  const float* Wo  = (const float*)d_in[7];
  const float* bo  = (const float*)d_in[8];
  const float* g1  = (const float*)d_in[9];
  const float* b1  = (const float*)d_in[10];
  const float* W1  = (const float*)d_in[11];
  const float* bm1 = (const float*)d_in[12];
  const float* W2  = (const float*)d_in[13];
  const float* bm2 = (const float*)d_in[14];
  const float* g2  = (const float*)d_in[15];
  const float* b2  = (const float*)d_in[16];
  float* out = (float*)d_out;

  char* ws = (char*)d_ws;
  const size_t MB = 1024 * 1024;
  ushort_t* xb    = (ushort_t*)(ws + 0);         // 8 MB   (dead after QKV gemm)
  ushort_t* wqkvt = (ushort_t*)(ws + 8 * MB);    // 6 MB
  ushort_t* wot   = (ushort_t*)(ws + 14 * MB);   // 2 MB
  ushort_t* w1t   = (ushort_t*)(ws + 16 * MB);   // 8 MB
  ushort_t* w2t   = (ushort_t*)(ws + 24 * MB);   // 8 MB
  ushort_t* qb    = (ushort_t*)(ws + 32 * MB);   // 8 MB   (dead after flash)
  ushort_t* kb    = (ushort_t*)(ws + 40 * MB);   // 8 MB   (dead after flash)
  ushort_t* vtb   = (ushort_t*)(ws + 48 * MB);   // 8 MB   (dead after flash)
  ushort_t* ctx   = (ushort_t*)(ws + 56 * MB);   // 8 MB   (dead after Wo gemm)
  float*    x1    = (float*)   (ws + 64 * MB);   // 16 MB
  ushort_t* x1b   = (ushort_t*)(ws + 80 * MB);   // 8 MB
  ushort_t* hbuf  = (ushort_t*)(ws + 88 * MB);   // 32 MB  (step 6-7 only)
  ushort_t* pWo   = (ushort_t*)(ws + 88 * MB);   // 32 MB over hbuf (step 4-5 only)
  ushort_t* pMd   = (ushort_t*)(ws + 32 * MB);   // 32 MB over qb..ctx (step 7-8)
  (void)ws_size; (void)in_sizes; (void)n_in; (void)out_size;

  // 1. fused prep: cast x + all weight transposes
  hipLaunchKernelGGL(prep_kernel, dim3(16384), dim3(256), 0, stream,
                     x, Wq, Wk, Wv, Wo, W1, W2, xb, wqkvt, wot, w1t, w2t);

  // 2. fused QKV projection (M=4096, N=3072, K=1024); V written transposed
  hipLaunchKernelGGL((gemm256<0>), dim3(192), dim3(512), 0, stream,
                     xb, wqkvt, NTOK, 3072, D_, 1024, 192, bq, bk, bv, qb, kb, vtb);

  // 3. attention (128-row q tiles)
  hipLaunchKernelGGL(flash_attn_kernel, dim3(4 * HH, SQLEN / 128), dim3(256), 0, stream,
                     qb, kb, vtb, ctx);

  // 4. output projection, split-K=4 -> bf16 partials pWo
  hipLaunchKernelGGL((gemm256<3>), dim3(256), dim3(512), 0, stream,
                     ctx, wot, NTOK, D_, D_, 256, 64,
                     (const float*)nullptr, (const float*)nullptr,
                     (const float*)nullptr, pWo, (ushort_t*)nullptr, (ushort_t*)nullptr);

  // 5. LN1 = LN(x + bo + sum partials) -> x1 (fp32) + x1b (bf16)
  hipLaunchKernelGGL((ln_red_kernel<4, 1>), dim3(NTOK), dim3(256), 0, stream,
                     pWo, bo, x, g1, b1, x1, x1b);

  // 6. MLP up + GELU -> hbuf (M=4096, N=4096, K=1024)
  hipLaunchKernelGGL((gemm256<2>), dim3(256), dim3(512), 0, stream,
                     x1b, w1t, NTOK, DFF_, D_, 1024, 256, bm1, (const float*)nullptr,
                     (const float*)nullptr, hbuf, (ushort_t*)nullptr, (ushort_t*)nullptr);

  // 7. MLP down, split-K=4 -> bf16 partials pMd
  hipLaunchKernelGGL((gemm256<3>), dim3(256), dim3(512), 0, stream,
                     hbuf, w2t, NTOK, D_, DFF_, 1024, 64,
                     (const float*)nullptr, (const float*)nullptr,
                     (const float*)nullptr, pMd, (ushort_t*)nullptr, (ushort_t*)nullptr);

  // 8. LN2 = LN(x1 + bm2 + sum partials) -> out
  hipLaunchKernelGGL((ln_red_kernel<4, 0>), dim3(NTOK), dim3(256), 0, stream,
                     pMd, bm2, x1, g2, b2, out, (ushort_t*)nullptr);
}

// Round 5
// 312.479 us; speedup vs baseline: 1.9842x; 1.9842x over previous
//
#include <hip/hip_runtime.h>

// Problem constants
#define D_    1024
#define HH    16
#define DHEAD 64
#define DFF_  4096
#define NTOK  4096   // B*S = 4*1024
#define SQLEN 1024

typedef unsigned short ushort_t;
typedef __attribute__((ext_vector_type(8))) short short8;
typedef __attribute__((ext_vector_type(4))) float floatx4;

#define LOG2E 1.44269504f

__device__ __forceinline__ unsigned short f2bf(float f) {
  union { float f; unsigned u; } x; x.f = f;
  unsigned r = x.u + 0x7fffu + ((x.u >> 16) & 1u);   // RNE
  return (unsigned short)(r >> 16);
}
__device__ __forceinline__ float bf2f(unsigned short u) {
  union { unsigned u; float f; } x; x.u = ((unsigned)u) << 16;
  return x.f;
}
// pack two fp32 -> bf16 pair in 3 ops (round-half-up + v_perm)
__device__ __forceinline__ unsigned pack2bf_fast(float a, float b) {
  union { float f; unsigned u; } x, y; x.f = a; y.f = b;
  return __builtin_amdgcn_perm(y.u + 0x8000u, x.u + 0x8000u, 0x07060302u);
}
__device__ __forceinline__ float fast_exp2(float x) {
  return __builtin_amdgcn_exp2f(x);
}
// gelu(u) = u - u * rcp(exp2(u*(c1 + c2*u^2)) + 1)
__device__ __forceinline__ float fast_gelu(float u) {
  float u2 = u * u;
  float arg = u * (2.30220414f + 0.10294307f * u2);
  float e = __builtin_amdgcn_exp2f(arg);
  float r = __builtin_amdgcn_rcpf(e + 1.0f);
  return u - u * r;
}

__device__ __forceinline__ void async_ld16(const void* g, void* l) {
  __builtin_amdgcn_global_load_lds(
      (const __attribute__((address_space(1))) unsigned int*)g,
      (__attribute__((address_space(3))) unsigned int*)l, 16, 0, 0);
}

// 32-bit LDS byte offset from a generic pointer to __shared__
__device__ __forceinline__ unsigned lds_off(const void* p) {
  return (unsigned)(unsigned long long)
      (const __attribute__((address_space(3))) char*)p;
}
// raw ds_read_b128: invisible to the compiler's vmcnt bookkeeping, so no
// implicit s_waitcnt vmcnt(0) drain is inserted before it (the counted
// VMW waits below are the only VMEM ordering).
__device__ __forceinline__ short8 ds_read128(unsigned addr) {
  short8 r;
  asm volatile("ds_read_b128 %0, %1" : "=v"(r) : "v"(addr));
  return r;
}

// ---------------- prep: cast x + all 6 weight transposes, one launch ----------------
__global__ __launch_bounds__(256) void prep_kernel(
    const float* __restrict__ x, const float* __restrict__ Wq,
    const float* __restrict__ Wk, const float* __restrict__ Wv,
    const float* __restrict__ Wo, const float* __restrict__ W1,
    const float* __restrict__ W2,
    ushort_t* __restrict__ xb, ushort_t* __restrict__ wqkvt,
    ushort_t* __restrict__ wot, ushort_t* __restrict__ w1t,
    ushort_t* __restrict__ w2t) {
  int bid = blockIdx.x, tid = threadIdx.x;
  if (bid < 4096) {
    int i = bid * 256 + tid;
    float4 v = ((const float4*)x)[i];
    ushort4 o;
    o.x = f2bf(v.x); o.y = f2bf(v.y); o.z = f2bf(v.z); o.w = f2bf(v.w);
    ((ushort4*)xb)[i] = o;
    return;
  }
  __shared__ float tile[32][33];
  const float* W; ushort_t* T; int K, N, n0, k0;
  if (bid < 8192) {
    int id = bid - 4096, z = id >> 10, xy = id & 1023;
    W = (z == 0) ? Wq : (z == 1) ? Wk : (z == 2) ? Wv : Wo;
    T = (z < 3) ? wqkvt + (size_t)z * D_ * D_ : wot;
    K = D_; N = D_;
    n0 = (xy & 31) * 32; k0 = (xy >> 5) * 32;
  } else if (bid < 12288) {
    int id = bid - 8192;
    W = W1; T = w1t; K = D_; N = DFF_;
    n0 = (id & 127) * 32; k0 = (id >> 7) * 32;
  } else {
    int id = bid - 12288;
    W = W2; T = w2t; K = DFF_; N = D_;
    n0 = (id & 31) * 32; k0 = (id >> 5) * 32;
  }
  int tx = tid & 31, ty = tid >> 5;
#pragma unroll
  for (int i = 0; i < 4; i++)
    tile[ty + i * 8][tx] = W[(size_t)(k0 + ty + i * 8) * N + n0 + tx];
  __syncthreads();
#pragma unroll
  for (int i = 0; i < 4; i++)
    T[(size_t)(n0 + ty + i * 8) * K + k0 + tx] = f2bf(tile[tx][ty + i * 8]);
}

// ---------------- 256x256 2-phase bf16 MFMA GEMM (B-held variant) ----------------
// 512 threads = 8 waves (2M x 4N), per-wave output 128x64, BK=64.
// LDS 128 KiB: 2 dbuf x 2 halves x [128][64] bf16 per operand.
// Chunk-XOR swizzle (chunk ^= row&7) BOTH sides (pre-swizzled global source
// for linear global_load_lds dest + same XOR on asm ds_read_b128).
// Register budget (8-wave block forces 2 waves/SIMD => <=256 regs/wave;
// acc=128 AGPR => arch VGPR <=128): operand sets a(8)+b0(4)+b1(4)=16 short8
// = 64 VGPR; round-3 was 48 => ~124 total. DO NOT add more sets (round-4
// spilled at 112 operand VGPRs: FETCH 22->220MB).
// Per K-tile, 2 phases, b0/b1 held across the tile (no B re-read; 24 reads):
//  Ph0: read A0,B0,B1 (16 ds); stage A0',B0'; lgkm(4)->C0(a,b0);
//       lgkm(0)->C1(a,b1); vmcnt(4) [drain A1]; bar
//  Ph1: read A1 (8 ds, overwrites a); stage B1',A1'; lgkm(0)->C2(a,b1);
//       C3(a,b0); vmcnt(2) [drain A0',B0',B1'; leave A1']; bar
// vmcnt ledger (2 loads/stage), steady state entry: {A1}=2 in flight.
// All LDS WAR distances >= 2 barriers (reads lgkm-drained in the phase that
// issues them; rewrites of the same region issued >=2 phases later).
// MODE 0: QKV. q,k -> [B][H][S][DH] bf16 (q scaled 0.125*log2e); v -> [B][H][DH][S]
// MODE 2: gelu(c + bias0[n]) -> bf16 o0[m][n]
// MODE 3: bf16 partial: o0[sp*M*N + m*N + n] = bf16(c)   (reduced in ln_red)
template <int MODE>
__global__ __launch_bounds__(512, 2) void gemm256(
    const ushort_t* __restrict__ A, const ushort_t* __restrict__ Bt,
    int M, int N, int K, int Ks, int nb,
    const float* __restrict__ bias0, const float* __restrict__ bias1,
    const float* __restrict__ bias2,
    ushort_t* __restrict__ o0, ushort_t* __restrict__ o1, ushort_t* __restrict__ o2) {
  __shared__ alignas(16) ushort_t sA[2][2][128 * 64];   // 64 KB
  __shared__ alignas(16) ushort_t sB[2][2][128 * 64];   // 64 KB
  int tid = threadIdx.x;
  int w = tid >> 6, lane = tid & 63, quad = lane >> 4, l16 = lane & 15;
  int wm = w >> 2, wn = w & 3;

  int sp = blockIdx.x / nb;
  int bid = blockIdx.x - sp * nb;
  int gridN = N >> 8;
  int Tn = nb >> 3;                     // tiles per XCD
  int lin = (bid & 7) * Tn + (bid >> 3);
  int ng = gridN << 3;                  // tiles per 8-row m-group
  int gidx = lin / ng;
  int rem = lin - gidx * ng;
  int m0 = ((gidx << 3) + (rem & 7)) << 8;
  int n0 = (rem >> 3) << 8;
  int kbeg = sp * Ks;
  int nkt = Ks >> 6;                    // >= 2

  floatx4 acc[8][4];
#pragma unroll
  for (int i = 0; i < 8; i++)
#pragma unroll
    for (int j = 0; j < 4; j++) acc[i][j] = (floatx4){0.f, 0.f, 0.f, 0.f};

  // ---- staging addresses (pre-swizzled global source, linear LDS dest) ----
  int s8  = tid >> 3;                       // 0..63
  int lcx = (tid & 7) ^ (s8 & 7);           // logical chunk for this thread
  const ushort_t* gA = A + (size_t)(m0 + s8) * K + kbeg + lcx * 8;
  const ushort_t* gB = Bt + (size_t)(n0 + (s8 & 31) + (s8 >> 5) * 64) * K + kbeg + lcx * 8;
  char* sta = (char*)&sA[0][0][0] + w * 1024;
  char* stb = (char*)&sB[0][0][0] + w * 1024;

  // ---- read addresses (swizzled chunk) as raw LDS byte offsets ----
  unsigned kof0 = (unsigned)((quad ^ (l16 & 7)) << 4);   // kc=0 chunk byte offset
  unsigned baseA = lds_off(&sA[0][0][0]) + (unsigned)((wm * 64 + l16) * 128);
  unsigned baseB = lds_off(&sB[0][0][0]) + (unsigned)((wn * 32 + l16) * 128);

#define STG_A(db, h, ko) { const ushort_t* _g = gA + (size_t)(h) * 64 * K + (ko); \
    char* _l = sta + (db) * 32768 + (h) * 16384; \
    async_ld16(_g, _l); async_ld16(_g + (size_t)128 * K, _l + 8192); }
#define STG_B(db, h, ko) { const ushort_t* _g = gB + (size_t)(h) * 32 * K + (ko); \
    char* _l = stb + (db) * 32768 + (h) * 16384; \
    async_ld16(_g, _l); async_ld16(_g + (size_t)128 * K, _l + 8192); }
#define LDSA(db, mq, DST) { unsigned _p = baseA + (db) * 32768u + (mq) * 16384u + kof0; \
    _Pragma("unroll") for (int mt = 0; mt < 4; mt++) { \
      DST[mt][0] = ds_read128(_p + (unsigned)(mt * 2048)); \
      DST[mt][1] = ds_read128((_p + (unsigned)(mt * 2048)) ^ 64u); } }
#define LDSB(db, nq, DST) { unsigned _p = baseB + (db) * 32768u + (nq) * 16384u + kof0; \
    _Pragma("unroll") for (int nt = 0; nt < 2; nt++) { \
      DST[nt][0] = ds_read128(_p + (unsigned)(nt * 2048)); \
      DST[nt][1] = ds_read128((_p + (unsigned)(nt * 2048)) ^ 64u); } }
#define MFMAC(mq, nq, A_, B_) { \
    _Pragma("unroll") for (int mt = 0; mt < 4; mt++) \
    _Pragma("unroll") for (int nt = 0; nt < 2; nt++) { \
      floatx4 c = acc[(mq) * 4 + mt][(nq) * 2 + nt]; \
      c = __builtin_amdgcn_mfma_f32_16x16x32_bf16(A_[mt][0], B_[nt][0], c, 0, 0, 0); \
      c = __builtin_amdgcn_mfma_f32_16x16x32_bf16(A_[mt][1], B_[nt][1], c, 0, 0, 0); \
      acc[(mq) * 4 + mt][(nq) * 2 + nt] = c; } }
#define BAR __builtin_amdgcn_s_barrier()
#define LGKC(n) { asm volatile("s_waitcnt lgkmcnt(" #n ")" ::: "memory"); \
                  __builtin_amdgcn_sched_barrier(0); }
#define VMW4 asm volatile("s_waitcnt vmcnt(4)" ::: "memory")
#define VMW2 asm volatile("s_waitcnt vmcnt(2)" ::: "memory")
#define VMW0 asm volatile("s_waitcnt vmcnt(0)" ::: "memory")
#define PRIO1 __builtin_amdgcn_s_setprio(1)
#define PRIO0 __builtin_amdgcn_s_setprio(0)

  short8 a[4][2], b0[2][2], b1[2][2];

  // prologue: stage tile0 (A0,B0,B1,A1); drain A0,B0,B1 (leave {A1}=2)
  STG_A(0, 0, 0); STG_B(0, 0, 0); STG_B(0, 1, 0); STG_A(0, 1, 0);
  VMW2; BAR;

  for (int kt = 0; kt < nkt - 1; kt++) {
    int db = kt & 1, dn = db ^ 1;
    int ko = (kt + 1) << 6;
    // Ph0: read A0,B0,B1; stage next A0,B0; C0,C1
    LDSA(db, 0, a); LDSB(db, 0, b0); LDSB(db, 1, b1);
    STG_A(dn, 0, ko); STG_B(dn, 0, ko);
    LGKC(4); PRIO1; MFMAC(0, 0, a, b0); PRIO0;
    LGKC(0); PRIO1; MFMAC(0, 1, a, b1); PRIO0;
    VMW4; BAR;
    // Ph1: read A1 (overwrite a); stage next B1,A1; C2,C3
    LDSA(db, 1, a);
    STG_B(dn, 1, ko); STG_A(dn, 1, ko);
    LGKC(0); PRIO1; MFMAC(1, 1, a, b1); PRIO0;
             PRIO1; MFMAC(1, 0, a, b0); PRIO0;
    VMW2; BAR;
  }
  {
    // final tile: no staging; drain remaining {A1}=2 at Ph0 end
    int db = (nkt - 1) & 1;
    LDSA(db, 0, a); LDSB(db, 0, b0); LDSB(db, 1, b1);
    LGKC(4); PRIO1; MFMAC(0, 0, a, b0); PRIO0;
    LGKC(0); PRIO1; MFMAC(0, 1, a, b1); PRIO0;
    VMW0; BAR;
    LDSA(db, 1, a);
    LGKC(0); PRIO1; MFMAC(1, 1, a, b1); PRIO0;
             PRIO1; MFMAC(1, 0, a, b0); PRIO0;
  }

  // ---------------- epilogue ----------------
  if (MODE == 0) {
#pragma unroll
    for (int bj = 0; bj < 4; bj++) {
      int cg = n0 + wn * 64 + (bj >> 1) * 32 + (bj & 1) * 16 + l16;
      int sel = cg >> 10, nn = cg & 1023;
      const float* bpp = (sel == 0) ? bias0 : ((sel == 1) ? bias1 : bias2);
      float bb = bpp[nn];
      int hh = nn >> 6, dd = nn & 63;
#pragma unroll
      for (int ai = 0; ai < 8; ai++) {
        int rg0 = m0 + wm * 128 + (ai >> 2) * 64 + (ai & 3) * 16 + quad * 4;
        int b0_ = rg0 >> 10, s0 = rg0 & 1023;
        if (sel == 2) {
          ushort4 ov;
          ov.x = f2bf(acc[ai][bj][0] + bb);
          ov.y = f2bf(acc[ai][bj][1] + bb);
          ov.z = f2bf(acc[ai][bj][2] + bb);
          ov.w = f2bf(acc[ai][bj][3] + bb);
          *(ushort4*)(o2 + ((size_t)(b0_ * HH + hh) * DHEAD + dd) * SQLEN + s0) = ov;
        } else {
          ushort_t* dst = sel ? o1 : o0;
          float sc = (sel == 0) ? (0.125f * LOG2E) : 1.0f;
#pragma unroll
          for (int r = 0; r < 4; r++)
            dst[((size_t)(b0_ * HH + hh) * SQLEN + s0 + r) * DHEAD + dd] =
                f2bf((acc[ai][bj][r] + bb) * sc);
        }
      }
    }
  } else {
    size_t rowbase = (size_t)(m0 + wm * 128 + quad * 4) * N + (n0 + wn * 64 + l16);
    if (MODE == 3) rowbase += (size_t)sp * M * N;
    float bb[4];
    if (MODE == 2) {
#pragma unroll
      for (int c = 0; c < 4; c++)
        bb[c] = bias0[(n0 + wn * 64 + c * 16 + l16) & (N - 1)];
    }
#pragma unroll
    for (int ai = 0; ai < 8; ai++) {
#pragma unroll
      for (int r = 0; r < 4; r++) {
        ushort_t* pr = o0 + rowbase + (size_t)((ai >> 2) * 64 + (ai & 3) * 16 + r) * N;
        if (MODE == 2) {
          pr[0]  = f2bf(fast_gelu(acc[ai][0][r] + bb[0]));
          pr[16] = f2bf(fast_gelu(acc[ai][1][r] + bb[1]));
          pr[32] = f2bf(fast_gelu(acc[ai][2][r] + bb[2]));
          pr[48] = f2bf(fast_gelu(acc[ai][3][r] + bb[3]));
        } else {
          pr[0]  = f2bf(acc[ai][0][r]);
          pr[16] = f2bf(acc[ai][1][r]);
          pr[32] = f2bf(acc[ai][2][r]);
          pr[48] = f2bf(acc[ai][3][r]);
        }
      }
    }
  }
#undef STG_A
#undef STG_B
#undef LDSA
#undef LDSB
#undef MFMAC
#undef BAR
#undef LGKC
#undef VMW4
#undef VMW2
#undef VMW0
#undef PRIO1
#undef PRIO0
}

// ---------------- flash attention (S^T form, 128-row q tiles) ----------------
// q,k: [B][H][S][DH] bf16 (q pre-scaled 0.125*log2e). vt: [B][H][DH][S] bf16.
// Block = (bh, 128-row q tile); wave owns 32 q rows (2 groups of 16).
// Fixed-reference exp2 softmax (no running max; scores tiny vs fp32 range).
__global__ __launch_bounds__(256) void flash_attn_kernel(const ushort_t* __restrict__ q,
                                                         const ushort_t* __restrict__ k,
                                                         const ushort_t* __restrict__ vt,
                                                         ushort_t* __restrict__ ctx) {
  __shared__ alignas(16) ushort_t sQ[2][128 * 32];    // 16 KB
  __shared__ alignas(16) ushort_t sK[2][64 * 32];     // 8 KB
  __shared__ alignas(16) ushort_t sVt[2][64 * 32];    // 8 KB
  __shared__ alignas(16) char sP[4][2][2][16 * 80];   // [wave][g][kc], 80B row stride
  int tid = threadIdx.x;
  int w = tid >> 6, lane = tid & 63, quad = lane >> 4, l16 = lane & 15;
  int bh = blockIdx.x, qt = blockIdx.y;
  int b_ = bh >> 4, h_ = bh & 15;

  const ushort_t* Qp = q + ((size_t)bh * SQLEN + qt * 128) * DHEAD;
  const ushort_t* Kp = k + (size_t)bh * SQLEN * DHEAD;
  const ushort_t* Vtp = vt + (size_t)bh * DHEAD * SQLEN;

  int srow = lane >> 2, scol8 = (lane & 3) * 8;

  // stage Q once: 128 rows x 64 cols -> 2 panels of [128][32]
#pragma unroll
  for (int h = 0; h < 2; h++)
#pragma unroll
    for (int p = 0; p < 2; p++)
      async_ld16(Qp + (h * 64 + w * 16 + srow) * 64 + p * 32 + scol8,
                 (char*)sQ + p * 8192 + (h * 64 + w * 16) * 64);

  float l_run[2] = {0.f, 0.f};
  floatx4 o_acc[2][4];
#pragma unroll
  for (int g = 0; g < 2; g++)
#pragma unroll
    for (int dt = 0; dt < 4; dt++) o_acc[g][dt] = (floatx4){0.f, 0.f, 0.f, 0.f};

  for (int kt = 0; kt < 16; kt++) {
    __syncthreads();
#pragma unroll
    for (int t = 0; t < 2; t++) {
      int id = w * 2 + t, panel = id & 1, rg = id >> 1;
      int row = rg * 16 + srow, col = panel * 32 + scol8;
      async_ld16(Kp + kt * 64 * 64 + row * 64 + col,
                 (char*)sK + panel * 4096 + rg * 1024);
      async_ld16(Vtp + (size_t)row * SQLEN + kt * 64 + col,
                 (char*)sVt + panel * 4096 + rg * 1024);
    }
    __syncthreads();

    // S^T = K Q^T for both q-groups (share kf loads)
    floatx4 st[2][4];
#pragma unroll
    for (int g = 0; g < 2; g++)
#pragma unroll
      for (int nt = 0; nt < 4; nt++) st[g][nt] = (floatx4){0.f, 0.f, 0.f, 0.f};
#pragma unroll
    for (int kc = 0; kc < 2; kc++) {
      short8 aq0 = *(const short8*)(sQ[kc] + (w * 32 + l16) * 32 + quad * 8);
      short8 aq1 = *(const short8*)(sQ[kc] + (w * 32 + 16 + l16) * 32 + quad * 8);
#pragma unroll
      for (int nt = 0; nt < 4; nt++) {
        short8 kf = *(const short8*)(sK[kc] + (nt * 16 + l16) * 32 + quad * 8);
        st[0][nt] = __builtin_amdgcn_mfma_f32_16x16x32_bf16(kf, aq0, st[0][nt], 0, 0, 0);
        st[1][nt] = __builtin_amdgcn_mfma_f32_16x16x32_bf16(kf, aq1, st[1][nt], 0, 0, 0);
      }
    }

    // p = exp2(score); per-lane l accumulate; pack + write P (B-operand layout)
#pragma unroll
    for (int g = 0; g < 2; g++) {
#pragma unroll
      for (int nt = 0; nt < 4; nt++) {
        float p0 = fast_exp2(st[g][nt][0]);
        float p1 = fast_exp2(st[g][nt][1]);
        float p2 = fast_exp2(st[g][nt][2]);
        float p3 = fast_exp2(st[g][nt][3]);
        l_run[g] += (p0 + p1) + (p2 + p3);
        uint2 d2;
        d2.x = pack2bf_fast(p0, p1);
        d2.y = pack2bf_fast(p2, p3);
        *(uint2*)(&sP[w][g][nt >> 1][0] + l16 * 80 + (nt & 1) * 32 + quad * 8) = d2;
      }
    }

    // O^T += V^T P^T (share vf loads across groups)
#pragma unroll
    for (int kc = 0; kc < 2; kc++) {
      short8 pf0 = *(const short8*)(&sP[w][0][kc][0] + l16 * 80 + quad * 16);
      short8 pf1 = *(const short8*)(&sP[w][1][kc][0] + l16 * 80 + quad * 16);
#pragma unroll
      for (int dt = 0; dt < 4; dt++) {
        short8 vf = *(const short8*)(sVt[kc] + (dt * 16 + l16) * 32 + quad * 8);
        o_acc[0][dt] = __builtin_amdgcn_mfma_f32_16x16x32_bf16(vf, pf0, o_acc[0][dt], 0, 0, 0);
        o_acc[1][dt] = __builtin_amdgcn_mfma_f32_16x16x32_bf16(vf, pf1, o_acc[1][dt], 0, 0, 0);
      }
    }
  }

#pragma unroll
  for (int g = 0; g < 2; g++) {
    float l = l_run[g];
    l += __shfl_xor(l, 16);
    l += __shfl_xor(l, 32);
    float inv = 1.f / fmaxf(l, 1e-30f);
    int s_ = qt * 128 + w * 32 + g * 16 + l16;
    ushort_t* cp = ctx + (size_t)(b_ * SQLEN + s_) * D_ + h_ * DHEAD + quad * 4;
#pragma unroll
    for (int dt = 0; dt < 4; dt++) {
      ushort4 ov;
      ov.x = f2bf(o_acc[g][dt][0] * inv);
      ov.y = f2bf(o_acc[g][dt][1] * inv);
      ov.z = f2bf(o_acc[g][dt][2] * inv);
      ov.w = f2bf(o_acc[g][dt][3] * inv);
      *(ushort4*)(cp + dt * 16) = ov;
    }
  }
}

// ---------------- LayerNorm with split-K partial reduction ----------------
template <int S, int WB>
__global__ __launch_bounds__(256) void ln_red_kernel(
    const ushort_t* __restrict__ parts, const float* __restrict__ bias,
    const float* __restrict__ res, const float* __restrict__ g,
    const float* __restrict__ b, float* __restrict__ outf,
    ushort_t* __restrict__ outb) {
  int row = blockIdx.x, tid = threadIdx.x;
  float4 v = ((const float4*)(res + (size_t)row * D_))[tid];
  float4 bb = ((const float4*)bias)[tid];
  v.x += bb.x; v.y += bb.y; v.z += bb.z; v.w += bb.w;
#pragma unroll
  for (int s = 0; s < S; s++) {
    ushort4 p = ((const ushort4*)(parts + (size_t)s * NTOK * D_ + (size_t)row * D_))[tid];
    v.x += bf2f(p.x); v.y += bf2f(p.y); v.z += bf2f(p.z); v.w += bf2f(p.w);
  }
  float s1 = v.x + v.y + v.z + v.w;
  float s2 = v.x * v.x + v.y * v.y + v.z * v.z + v.w * v.w;
#pragma unroll
  for (int off = 32; off > 0; off >>= 1) {
    s1 += __shfl_down(s1, off);
    s2 += __shfl_down(s2, off);
  }
  __shared__ float red[10];
  int wid = tid >> 6, lane = tid & 63;
  if (lane == 0) { red[wid] = s1; red[4 + wid] = s2; }
  __syncthreads();
  if (tid == 0) {
    float ts = red[0] + red[1] + red[2] + red[3];
    float ts2 = red[4] + red[5] + red[6] + red[7];
    float mu = ts * (1.f / 1024.f);
    float var = ts2 * (1.f / 1024.f) - mu * mu;
    red[8] = mu;
    red[9] = rsqrtf(var + 1e-5f);
  }
  __syncthreads();
  float mu = red[8], rsg = red[9];
  float4 gv = ((const float4*)g)[tid];
  float4 bv = ((const float4*)b)[tid];
  float4 o;
  o.x = (v.x - mu) * rsg * gv.x + bv.x;
  o.y = (v.y - mu) * rsg * gv.y + bv.y;
  o.z = (v.z - mu) * rsg * gv.z + bv.z;
  o.w = (v.w - mu) * rsg * gv.w + bv.w;
  if (outf) ((float4*)(outf + (size_t)row * D_))[tid] = o;
  if (WB) {
    ushort4 ob;
    ob.x = f2bf(o.x); ob.y = f2bf(o.y); ob.z = f2bf(o.z); ob.w = f2bf(o.w);
    ((ushort4*)(outb + (size_t)row * D_))[tid] = ob;
  }
}

extern "C" void kernel_launch(void* const* d_in, const int* in_sizes, int n_in,
                              void* d_out, int out_size, void* d_ws, size_t ws_size,
                              hipStream_t stream) {
  const float* x   = (const float*)d_in[0];
  const float* Wq  = (const float*)d_in[1];
  const float* bq  = (const float*)d_in[2];
  const float* Wk  = (const float*)d_in[3];
  const float* bk  = (const float*)d_in[4];
  const float* Wv  = (const float*)d_in[5];
  const float* bv  = (const float*)d_in[6];
  const float* Wo  = (const float*)d_in[7];
  const float* bo  = (const float*)d_in[8];
  const float* g1  = (const float*)d_in[9];
  const float* b1  = (const float*)d_in[10];
  const float* W1  = (const float*)d_in[11];
  const float* bm1 = (const float*)d_in[12];
  const float* W2  = (const float*)d_in[13];
  const float* bm2 = (const float*)d_in[14];
  const float* g2  = (const float*)d_in[15];
  const float* b2  = (const float*)d_in[16];
  float* out = (float*)d_out;

  char* ws = (char*)d_ws;
  const size_t MB = 1024 * 1024;
  ushort_t* xb    = (ushort_t*)(ws + 0);         // 8 MB   (dead after QKV gemm)
  ushort_t* wqkvt = (ushort_t*)(ws + 8 * MB);    // 6 MB
  ushort_t* wot   = (ushort_t*)(ws + 14 * MB);   // 2 MB
  ushort_t* w1t   = (ushort_t*)(ws + 16 * MB);   // 8 MB
  ushort_t* w2t   = (ushort_t*)(ws + 24 * MB);   // 8 MB
  ushort_t* qb    = (ushort_t*)(ws + 32 * MB);   // 8 MB   (dead after flash)
  ushort_t* kb    = (ushort_t*)(ws + 40 * MB);   // 8 MB   (dead after flash)
  ushort_t* vtb   = (ushort_t*)(ws + 48 * MB);   // 8 MB   (dead after flash)
  ushort_t* ctx   = (ushort_t*)(ws + 56 * MB);   // 8 MB   (dead after Wo gemm)
  float*    x1    = (float*)   (ws + 64 * MB);   // 16 MB
  ushort_t* x1b   = (ushort_t*)(ws + 80 * MB);   // 8 MB
  ushort_t* hbuf  = (ushort_t*)(ws + 88 * MB);   // 32 MB  (step 6-7 only)
  ushort_t* pWo   = (ushort_t*)(ws + 88 * MB);   // 32 MB over hbuf (step 4-5 only)
  ushort_t* pMd   = (ushort_t*)(ws + 32 * MB);   // 32 MB over qb..ctx (step 7-8)
  (void)ws_size; (void)in_sizes; (void)n_in; (void)out_size;

  // 1. fused prep: cast x + all weight transposes
  hipLaunchKernelGGL(prep_kernel, dim3(16384), dim3(256), 0, stream,
                     x, Wq, Wk, Wv, Wo, W1, W2, xb, wqkvt, wot, w1t, w2t);

  // 2. fused QKV projection (M=4096, N=3072, K=1024); V written transposed
  hipLaunchKernelGGL((gemm256<0>), dim3(192), dim3(512), 0, stream,
                     xb, wqkvt, NTOK, 3072, D_, 1024, 192, bq, bk, bv, qb, kb, vtb);

  // 3. attention (128-row q tiles)
  hipLaunchKernelGGL(flash_attn_kernel, dim3(4 * HH, SQLEN / 128), dim3(256), 0, stream,
                     qb, kb, vtb, ctx);

  // 4. output projection, split-K=4 -> bf16 partials pWo
  hipLaunchKernelGGL((gemm256<3>), dim3(256), dim3(512), 0, stream,
                     ctx, wot, NTOK, D_, D_, 256, 64,
                     (const float*)nullptr, (const float*)nullptr,
                     (const float*)nullptr, pWo, (ushort_t*)nullptr, (ushort_t*)nullptr);

  // 5. LN1 = LN(x + bo + sum partials) -> x1 (fp32) + x1b (bf16)
  hipLaunchKernelGGL((ln_red_kernel<4, 1>), dim3(NTOK), dim3(256), 0, stream,
                     pWo, bo, x, g1, b1, x1, x1b);

  // 6. MLP up + GELU -> hbuf (M=4096, N=4096, K=1024)
  hipLaunchKernelGGL((gemm256<2>), dim3(256), dim3(512), 0, stream,
                     x1b, w1t, NTOK, DFF_, D_, 1024, 256, bm1, (const float*)nullptr,
                     (const float*)nullptr, hbuf, (ushort_t*)nullptr, (ushort_t*)nullptr);

  // 7. MLP down, split-K=4 -> bf16 partials pMd
  hipLaunchKernelGGL((gemm256<3>), dim3(256), dim3(512), 0, stream,
                     hbuf, w2t, NTOK, D_, DFF_, 1024, 64,
                     (const float*)nullptr, (const float*)nullptr,
                     (const float*)nullptr, pMd, (ushort_t*)nullptr, (ushort_t*)nullptr);

  // 8. LN2 = LN(x1 + bm2 + sum partials) -> out
  hipLaunchKernelGGL((ln_red_kernel<4, 0>), dim3(NTOK), dim3(256), 0, stream,
                     pMd, bm2, x1, g2, b2, out, (ushort_t*)nullptr);
}